// Round 1
// baseline (665.880 us; speedup 1.0000x reference)
//
#include <hip/hip_runtime.h>
#include <cstdint>

#define FEAT 64
#define NEG_SLOPE 0.2f
#define ENC_NEGINF 0x007FFFFFu

// ---------- small helpers ----------

__global__ void dotc_kernel(const float* __restrict__ a, const float* __restrict__ b,
                            float* __restrict__ out) {
    int lane = threadIdx.x;
    float v = a[lane] * b[lane];
    #pragma unroll
    for (int off = 32; off; off >>= 1) v += __shfl_xor(v, off, 64);
    if (lane == 0) *out = v;
}

__global__ void init_seg_kernel(unsigned* __restrict__ smax, float* __restrict__ den, int N) {
    int i = blockIdx.x * blockDim.x + threadIdx.x;
    if (i < N) { smax[i] = ENC_NEGINF; den[i] = 0.0f; }
}

__global__ void init_out_kernel(float* __restrict__ OUT, const float* __restrict__ bias, int N) {
    int idx = blockIdx.x * blockDim.x + threadIdx.x;
    int row = idx >> 6, lane = idx & 63;
    if (row < N) OUT[row * FEAT + lane] = bias[lane];
}

// ---------- GEMM (h = x @ W) fused with attention dots ----------
// 256 threads = 4 waves; each wave does 4 rows; W staged in LDS.
template <bool RELU_IN>
__global__ void gemm_att_kernel(const float* __restrict__ X, const float* __restrict__ W,
                                const float* __restrict__ att_s, const float* __restrict__ att_d,
                                float* __restrict__ H, float* __restrict__ a_src,
                                float* __restrict__ a_dst, int N) {
    __shared__ float Ws[FEAT * FEAT];
    int tid = threadIdx.x;
    #pragma unroll
    for (int i = 0; i < 16; ++i) Ws[tid + i * 256] = W[tid + i * 256];
    __syncthreads();

    int wave = tid >> 6, lane = tid & 63;
    int row0 = blockIdx.x * 16 + wave * 4;
    float as_w = att_s[lane], ad_w = att_d[lane];
    for (int r = 0; r < 4; ++r) {
        int row = row0 + r;
        if (row >= N) return;
        float xv = X[row * FEAT + lane];
        if (RELU_IN) xv = fmaxf(xv, 0.0f);
        float acc = 0.0f;
        #pragma unroll
        for (int k = 0; k < FEAT; ++k) {
            float xk = __shfl(xv, k, 64);
            acc = fmaf(xk, Ws[k * FEAT + lane], acc);
        }
        H[row * FEAT + lane] = acc;
        float s = acc * as_w;
        float d = acc * ad_w;
        #pragma unroll
        for (int off = 32; off; off >>= 1) {
            s += __shfl_xor(s, off, 64);
            d += __shfl_xor(d, off, 64);
        }
        if (lane == 0) { a_src[row] = s; a_dst[row] = d; }
    }
}

// ---------- edge pass 1: logits + segment max ----------
__global__ void edge_logits_kernel(const int* __restrict__ src, const int* __restrict__ dst,
                                   const float* __restrict__ eattr,
                                   const float* __restrict__ a_src, const float* __restrict__ a_dst,
                                   const float* __restrict__ cptr,
                                   float* __restrict__ logits, unsigned* __restrict__ smax, int E) {
    int e = blockIdx.x * blockDim.x + threadIdx.x;
    if (e >= E) return;
    float c = *cptr;
    float l = a_src[src[e]] + a_dst[dst[e]] + eattr[e] * c;
    l = (l > 0.0f) ? l : NEG_SLOPE * l;
    logits[e] = l;
    unsigned b = __float_as_uint(l);
    unsigned key = (b & 0x80000000u) ? ~b : (b | 0x80000000u);
    atomicMax(&smax[dst[e]], key);
}

// ---------- edge pass 2: exp + segment sum ----------
__global__ void edge_exp_kernel(const int* __restrict__ dst, const unsigned* __restrict__ smax,
                                float* __restrict__ num_io, float* __restrict__ den, int E) {
    int e = blockIdx.x * blockDim.x + threadIdx.x;
    if (e >= E) return;
    int d = dst[e];
    unsigned u = smax[d];
    float m = (u >> 31) ? __uint_as_float(u ^ 0x80000000u) : __uint_as_float(~u);
    if (!isfinite(m)) m = 0.0f;
    float num = __expf(num_io[e] - m);
    num_io[e] = num;
    atomicAdd(&den[d], num);
}

// ---------- edge pass 3: weighted scatter-add ----------
__global__ void aggregate_kernel(const int* __restrict__ src, const int* __restrict__ dst,
                                 const float* __restrict__ num, const float* __restrict__ den,
                                 const float* __restrict__ H, float* __restrict__ OUT, int E) {
    int idx = blockIdx.x * blockDim.x + threadIdx.x;
    int e = idx >> 6, lane = idx & 63;
    if (e >= E) return;
    int s = src[e], d = dst[e];
    float alpha = num[e] / (den[d] + 1e-16f);
    atomicAdd(&OUT[d * FEAT + lane], alpha * H[s * FEAT + lane]);
}

// ---------- host ----------

static inline size_t align256(size_t x) { return (x + 255) & ~size_t(255); }

extern "C" void kernel_launch(void* const* d_in, const int* in_sizes, int n_in,
                              void* d_out, int out_size, void* d_ws, size_t ws_size,
                              hipStream_t stream) {
    const float* x        = (const float*)d_in[0];
    const int*   eidx     = (const int*)d_in[1];
    const float* eattr    = (const float*)d_in[2];
    const float* W1       = (const float*)d_in[3];
    const float* att_s1   = (const float*)d_in[4];
    const float* att_d1   = (const float*)d_in[5];
    const float* We1      = (const float*)d_in[6];
    const float* att_e1   = (const float*)d_in[7];
    const float* b1       = (const float*)d_in[8];
    const float* W2       = (const float*)d_in[9];
    const float* att_s2   = (const float*)d_in[10];
    const float* att_d2   = (const float*)d_in[11];
    const float* We2      = (const float*)d_in[12];
    const float* att_e2   = (const float*)d_in[13];
    const float* b2       = (const float*)d_in[14];
    float* OUT = (float*)d_out;

    const int N = in_sizes[0] / FEAT;
    const int E = in_sizes[2];
    const int* src = eidx;
    const int* dst = eidx + E;

    // workspace layout
    char* ws = (char*)d_ws;
    size_t off = 0;
    float* h1    = (float*)(ws + off); off = align256(off + (size_t)N * FEAT * 4);
    float* out1  = (float*)(ws + off); off = align256(off + (size_t)N * FEAT * 4);
    float* a_src = (float*)(ws + off); off = align256(off + (size_t)N * 4);
    float* a_dst = (float*)(ws + off); off = align256(off + (size_t)N * 4);
    unsigned* smax = (unsigned*)(ws + off); off = align256(off + (size_t)N * 4);
    float* den   = (float*)(ws + off); off = align256(off + (size_t)N * 4);
    float* elog  = (float*)(ws + off); off = align256(off + (size_t)E * 4);  // logits -> num (in place)
    float* cbuf  = (float*)(ws + off); off = align256(off + 2 * 4);
    (void)ws_size;

    const int nodeBlocks  = (N + 255) / 256;
    const int rowBlocks   = (N * FEAT + 255) / 256;   // for init_out
    const int gemmBlocks  = (N + 15) / 16;
    const int edgeBlocks  = (E + 255) / 256;
    const int aggBlocks   = ((size_t)E * FEAT + 255) / 256;

    // edge scalar coefficients c = dot(We, att_e)
    dotc_kernel<<<1, 64, 0, stream>>>(We1, att_e1, cbuf + 0);
    dotc_kernel<<<1, 64, 0, stream>>>(We2, att_e2, cbuf + 1);

    // ===== layer 1 =====
    gemm_att_kernel<false><<<gemmBlocks, 256, 0, stream>>>(x, W1, att_s1, att_d1, h1, a_src, a_dst, N);
    init_seg_kernel<<<nodeBlocks, 256, 0, stream>>>(smax, den, N);
    init_out_kernel<<<rowBlocks, 256, 0, stream>>>(out1, b1, N);
    edge_logits_kernel<<<edgeBlocks, 256, 0, stream>>>(src, dst, eattr, a_src, a_dst, cbuf + 0, elog, smax, E);
    edge_exp_kernel<<<edgeBlocks, 256, 0, stream>>>(dst, smax, elog, den, E);
    aggregate_kernel<<<aggBlocks, 256, 0, stream>>>(src, dst, elog, den, h1, out1, E);

    // ===== layer 2 (ReLU applied on input read) =====
    gemm_att_kernel<true><<<gemmBlocks, 256, 0, stream>>>(out1, W2, att_s2, att_d2, h1, a_src, a_dst, N);
    init_seg_kernel<<<nodeBlocks, 256, 0, stream>>>(smax, den, N);
    init_out_kernel<<<rowBlocks, 256, 0, stream>>>(OUT, b2, N);
    edge_logits_kernel<<<edgeBlocks, 256, 0, stream>>>(src, dst, eattr, a_src, a_dst, cbuf + 1, elog, smax, E);
    edge_exp_kernel<<<edgeBlocks, 256, 0, stream>>>(dst, smax, elog, den, E);
    aggregate_kernel<<<aggBlocks, 256, 0, stream>>>(src, dst, elog, den, h1, OUT, E);
}

// Round 2
// 334.175 us; speedup vs baseline: 1.9926x; 1.9926x over previous
//
#include <hip/hip_runtime.h>
#include <cstdint>

#define FEAT 64
#define NEG_SLOPE 0.2f

// ---------- tiny helpers ----------

__global__ void dotc_kernel(const float* __restrict__ a, const float* __restrict__ b,
                            float* __restrict__ out) {
    int lane = threadIdx.x;
    float v = a[lane] * b[lane];
    #pragma unroll
    for (int off = 32; off; off >>= 1) v += __shfl_xor(v, off, 64);
    if (lane == 0) *out = v;
}

// ---------- CSR build ----------

__global__ void hist_kernel(const int* __restrict__ dst, int* __restrict__ deg, int E) {
    int e = blockIdx.x * blockDim.x + threadIdx.x;
    if (e < E) atomicAdd(&deg[dst[e]], 1);
}

// inclusive scan of `in[0..n)` in blocks of 256; per-block inclusive result in
// `partial`, per-block totals in `bsum` (may be null).
__global__ void scan_block_kernel(const int* __restrict__ in, int* __restrict__ partial,
                                  int* __restrict__ bsum, int n) {
    int tid = threadIdx.x;
    int i = blockIdx.x * 256 + tid;
    int lane = tid & 63, wave = tid >> 6;
    int v = (i < n) ? in[i] : 0;
    #pragma unroll
    for (int off = 1; off < 64; off <<= 1) {
        int t = __shfl_up(v, off, 64);
        if (lane >= off) v += t;
    }
    __shared__ int wsum[4];
    if (lane == 63) wsum[wave] = v;
    __syncthreads();
    int add = 0;
    for (int w = 0; w < wave; ++w) add += wsum[w];
    v += add;
    if (i < n) partial[i] = v;
    if (tid == 255 && bsum) bsum[blockIdx.x] = v;
}

__global__ void scan_finalize_kernel(const int* __restrict__ partial, const int* __restrict__ bsumS,
                                     const int* __restrict__ deg, int* __restrict__ rowptr,
                                     int* __restrict__ cursor, int N, int E) {
    int i = blockIdx.x * 256 + threadIdx.x;
    if (i >= N) return;
    int T = partial[i] + (blockIdx.x > 0 ? bsumS[blockIdx.x - 1] : 0);
    int r = T - deg[i];            // exclusive scan
    rowptr[i] = r;
    cursor[i] = r;
    if (i == N - 1) rowptr[N] = E;
}

__global__ void scatter_kernel(const int* __restrict__ src, const int* __restrict__ dst,
                               const float* __restrict__ eattr, int* __restrict__ cursor,
                               int* __restrict__ esrc, float* __restrict__ eap, int E) {
    int e = blockIdx.x * blockDim.x + threadIdx.x;
    if (e >= E) return;
    int pos = atomicAdd(&cursor[dst[e]], 1);
    esrc[pos] = src[e];
    eap[pos] = eattr[e];
}

// ---------- GEMM (h = act(x) @ W) fused with attention dots ----------
template <bool RELU_IN>
__global__ void gemm_att_kernel(const float* __restrict__ X, const float* __restrict__ W,
                                const float* __restrict__ att_s, const float* __restrict__ att_d,
                                float* __restrict__ H, float* __restrict__ a_src,
                                float* __restrict__ a_dst, int N) {
    __shared__ float Ws[FEAT * FEAT];
    int tid = threadIdx.x;
    #pragma unroll
    for (int i = 0; i < 16; ++i) Ws[tid + i * 256] = W[tid + i * 256];
    __syncthreads();

    int wave = tid >> 6, lane = tid & 63;
    int row0 = blockIdx.x * 16 + wave * 4;
    float as_w = att_s[lane], ad_w = att_d[lane];
    for (int r = 0; r < 4; ++r) {
        int row = row0 + r;
        if (row >= N) return;
        float xv = X[row * FEAT + lane];
        if (RELU_IN) xv = fmaxf(xv, 0.0f);
        float acc = 0.0f;
        #pragma unroll
        for (int k = 0; k < FEAT; ++k) {
            float xk = __shfl(xv, k, 64);
            acc = fmaf(xk, Ws[k * FEAT + lane], acc);
        }
        H[row * FEAT + lane] = acc;
        float s = acc * as_w;
        float d = acc * ad_w;
        #pragma unroll
        for (int off = 32; off; off >>= 1) {
            s += __shfl_xor(s, off, 64);
            d += __shfl_xor(d, off, 64);
        }
        if (lane == 0) { a_src[row] = s; a_dst[row] = d; }
    }
}

// ---------- fused per-node softmax + aggregate (flash-style) ----------
// wave = node, lane = feature. Edges of the node are contiguous in CSR order.
__global__ void fused_agg_kernel(const int* __restrict__ rowptr, const int* __restrict__ esrc,
                                 const float* __restrict__ eap,
                                 const float* __restrict__ a_src, const float* __restrict__ a_dst,
                                 const float* __restrict__ cptr, const float* __restrict__ H,
                                 const float* __restrict__ bias, float* __restrict__ OUT, int N) {
    int wave = threadIdx.x >> 6, lane = threadIdx.x & 63;
    int node = blockIdx.x * (blockDim.x >> 6) + wave;
    if (node >= N) return;
    int beg = rowptr[node], end = rowptr[node + 1];
    float c = *cptr;
    float adn = a_dst[node];
    float bval = bias[lane];
    float m = -INFINITY, den = 0.0f, acc = 0.0f;

    for (int base = beg; base < end; base += 64) {
        int j = base + lane;
        int s = 0;
        float l = -INFINITY;
        if (j < end) {
            s = esrc[j];
            l = a_src[s] + adn + c * eap[j];
            l = (l > 0.0f) ? l : NEG_SLOPE * l;
        }
        // chunk max
        float cm = l;
        #pragma unroll
        for (int off = 32; off; off >>= 1) cm = fmaxf(cm, __shfl_xor(cm, off, 64));
        if (cm > m) {
            float sc = __expf(m - cm);   // m==-inf on first chunk -> sc = 0
            acc *= sc;
            den *= sc;
            m = cm;
        }
        float w = (j < end) ? __expf(l - m) : 0.0f;
        int cnt = end - base; if (cnt > 64) cnt = 64;
        for (int k = 0; k < cnt; ++k) {
            int   sk = __shfl(s, k, 64);
            float wk = __shfl(w, k, 64);
            den += wk;
            acc = fmaf(wk, H[(size_t)sk * FEAT + lane], acc);
        }
    }
    OUT[(size_t)node * FEAT + lane] = acc / (den + 1e-16f) + bval;
}

// ---------- host ----------

static inline size_t align256(size_t x) { return (x + 255) & ~size_t(255); }

extern "C" void kernel_launch(void* const* d_in, const int* in_sizes, int n_in,
                              void* d_out, int out_size, void* d_ws, size_t ws_size,
                              hipStream_t stream) {
    const float* x        = (const float*)d_in[0];
    const int*   eidx     = (const int*)d_in[1];
    const float* eattr    = (const float*)d_in[2];
    const float* W1       = (const float*)d_in[3];
    const float* att_s1   = (const float*)d_in[4];
    const float* att_d1   = (const float*)d_in[5];
    const float* We1      = (const float*)d_in[6];
    const float* att_e1   = (const float*)d_in[7];
    const float* b1       = (const float*)d_in[8];
    const float* W2       = (const float*)d_in[9];
    const float* att_s2   = (const float*)d_in[10];
    const float* att_d2   = (const float*)d_in[11];
    const float* We2      = (const float*)d_in[12];
    const float* att_e2   = (const float*)d_in[13];
    const float* b2       = (const float*)d_in[14];
    float* OUT = (float*)d_out;

    const int N = in_sizes[0] / FEAT;
    const int E = in_sizes[2];
    const int* src = eidx;
    const int* dst = eidx + E;

    // workspace layout
    char* ws = (char*)d_ws;
    size_t off = 0;
    float* h     = (float*)(ws + off); off = align256(off + (size_t)N * FEAT * 4);
    float* out1  = (float*)(ws + off); off = align256(off + (size_t)N * FEAT * 4);
    float* a_src = (float*)(ws + off); off = align256(off + (size_t)N * 4);
    float* a_dst = (float*)(ws + off); off = align256(off + (size_t)N * 4);
    int*   deg    = (int*)(ws + off); off = align256(off + (size_t)N * 4);
    int*   partial= (int*)(ws + off); off = align256(off + (size_t)N * 4);
    int*   rowptr = (int*)(ws + off); off = align256(off + (size_t)(N + 1) * 4);
    int*   cursor = (int*)(ws + off); off = align256(off + (size_t)N * 4);
    int*   bsum   = (int*)(ws + off); off = align256(off + 1024 * 4);
    int*   bsumS  = (int*)(ws + off); off = align256(off + 1024 * 4);
    int*   esrc   = (int*)(ws + off); off = align256(off + (size_t)E * 4);
    float* eap   = (float*)(ws + off); off = align256(off + (size_t)E * 4);
    float* cbuf  = (float*)(ws + off); off = align256(off + 2 * 4);
    (void)ws_size;

    const int nb         = (N + 255) / 256;            // scan blocks (196 <= 256)
    const int gemmBlocks = (N + 15) / 16;
    const int edgeBlocks = (E + 255) / 256;
    const int aggBlocks  = (N + 3) / 4;                // 4 waves/block, wave=node

    // edge scalar coefficients c = dot(We, att_e)
    dotc_kernel<<<1, 64, 0, stream>>>(We1, att_e1, cbuf + 0);
    dotc_kernel<<<1, 64, 0, stream>>>(We2, att_e2, cbuf + 1);

    // ===== CSR build (once; shared by both layers) =====
    hipMemsetAsync(deg, 0, (size_t)N * 4, stream);
    hist_kernel<<<edgeBlocks, 256, 0, stream>>>(dst, deg, E);
    scan_block_kernel<<<nb, 256, 0, stream>>>(deg, partial, bsum, N);
    scan_block_kernel<<<1, 256, 0, stream>>>(bsum, bsumS, nullptr, nb);
    scan_finalize_kernel<<<nb, 256, 0, stream>>>(partial, bsumS, deg, rowptr, cursor, N, E);
    scatter_kernel<<<edgeBlocks, 256, 0, stream>>>(src, dst, eattr, cursor, esrc, eap, E);

    // ===== layer 1 =====
    gemm_att_kernel<false><<<gemmBlocks, 256, 0, stream>>>(x, W1, att_s1, att_d1, h, a_src, a_dst, N);
    fused_agg_kernel<<<aggBlocks, 256, 0, stream>>>(rowptr, esrc, eap, a_src, a_dst, cbuf + 0, h, b1, out1, N);

    // ===== layer 2 (ReLU applied on input read inside gemm) =====
    gemm_att_kernel<true><<<gemmBlocks, 256, 0, stream>>>(out1, W2, att_s2, att_d2, h, a_src, a_dst, N);
    fused_agg_kernel<<<aggBlocks, 256, 0, stream>>>(rowptr, esrc, eap, a_src, a_dst, cbuf + 1, h, b2, OUT, N);
}

// Round 3
// 316.567 us; speedup vs baseline: 2.1034x; 1.0556x over previous
//
#include <hip/hip_runtime.h>
#include <cstdint>

#define FEAT 64
#define NEG_SLOPE 0.2f
#define TROWS 32

// ---------- prep: cbuf[b] = dot(We_b, att_e_b) ----------
__global__ void prep_kernel(const float* __restrict__ We1, const float* __restrict__ ae1,
                            const float* __restrict__ We2, const float* __restrict__ ae2,
                            float* __restrict__ cbuf) {
    int lane = threadIdx.x;
    const float* a = blockIdx.x ? We2 : We1;
    const float* b = blockIdx.x ? ae2 : ae1;
    float v = a[lane] * b[lane];
    #pragma unroll
    for (int off = 32; off; off >>= 1) v += __shfl_xor(v, off, 64);
    if (lane == 0) cbuf[blockIdx.x] = v;
}

// ---------- CSR build ----------

__global__ void hist_kernel(const int* __restrict__ dst, int* __restrict__ deg, int E) {
    int e = blockIdx.x * blockDim.x + threadIdx.x;
    if (e < E) atomicAdd(&deg[dst[e]], 1);
}

__global__ void scan_block_kernel(const int* __restrict__ in, int* __restrict__ partial,
                                  int* __restrict__ bsum, int n) {
    int tid = threadIdx.x;
    int i = blockIdx.x * 256 + tid;
    int lane = tid & 63, wave = tid >> 6;
    int v = (i < n) ? in[i] : 0;
    #pragma unroll
    for (int off = 1; off < 64; off <<= 1) {
        int t = __shfl_up(v, off, 64);
        if (lane >= off) v += t;
    }
    __shared__ int wsum[4];
    if (lane == 63) wsum[wave] = v;
    __syncthreads();
    int add = 0;
    for (int w = 0; w < wave; ++w) add += wsum[w];
    v += add;
    if (i < n) partial[i] = v;
    if (tid == 255 && bsum) bsum[blockIdx.x] = v;
}

__global__ void scan_finalize_kernel(const int* __restrict__ partial, const int* __restrict__ bsumS,
                                     const int* __restrict__ deg, int* __restrict__ rowptr,
                                     int* __restrict__ cursor, int N, int E) {
    int i = blockIdx.x * 256 + threadIdx.x;
    if (i >= N) return;
    int T = partial[i] + (blockIdx.x > 0 ? bsumS[blockIdx.x - 1] : 0);
    int r = T - deg[i];            // exclusive scan
    rowptr[i] = r;
    cursor[i] = r;
    if (i == N - 1) rowptr[N] = E;
}

__global__ void scatter_kernel(const int* __restrict__ src, const int* __restrict__ dst,
                               const float* __restrict__ eattr, int* __restrict__ cursor,
                               int2* __restrict__ epack, int E) {
    int e = blockIdx.x * blockDim.x + threadIdx.x;
    if (e >= E) return;
    int pos = atomicAdd(&cursor[dst[e]], 1);
    epack[pos] = make_int2(src[e], __float_as_int(eattr[e]));
}

// ---------- GEMM (h = act(x) @ W) fused with attention dots ----------
// 256 threads = 4 waves; 32-row tile; wave w computes rows w*8..w*8+7 with acc[8].
template <bool RELU_IN>
__global__ __launch_bounds__(256) void gemm_att_kernel(
        const float* __restrict__ X, const float* __restrict__ W,
        const float* __restrict__ att_s, const float* __restrict__ att_d,
        float* __restrict__ H, float* __restrict__ a_src,
        float* __restrict__ a_dst, int N) {
    __shared__ float Ws[FEAT * FEAT];
    __shared__ float Xs[TROWS * FEAT];
    int tid = threadIdx.x;

    const float4* W4 = (const float4*)W;
    float4* Ws4 = (float4*)Ws;
    #pragma unroll
    for (int i = 0; i < 4; ++i) Ws4[tid + i * 256] = W4[tid + i * 256];

    int row0 = blockIdx.x * TROWS;
    const float4* X4 = (const float4*)(X + (size_t)row0 * FEAT);
    float4* Xs4 = (float4*)Xs;
    #pragma unroll
    for (int i = 0; i < 2; ++i) {
        int idx = tid + i * 256;          // 512 float4 = 32 rows * 16
        int r = idx >> 4;
        float4 v = make_float4(0.f, 0.f, 0.f, 0.f);
        if (row0 + r < N) v = X4[idx];
        if (RELU_IN) {
            v.x = fmaxf(v.x, 0.f); v.y = fmaxf(v.y, 0.f);
            v.z = fmaxf(v.z, 0.f); v.w = fmaxf(v.w, 0.f);
        }
        Xs4[idx] = v;
    }
    __syncthreads();

    int wave = tid >> 6, lane = tid & 63;
    int wrow = wave * 8;
    float acc[8] = {0.f, 0.f, 0.f, 0.f, 0.f, 0.f, 0.f, 0.f};
    #pragma unroll
    for (int k4 = 0; k4 < 16; ++k4) {
        float w0 = Ws[(k4 * 4 + 0) * FEAT + lane];
        float w1 = Ws[(k4 * 4 + 1) * FEAT + lane];
        float w2 = Ws[(k4 * 4 + 2) * FEAT + lane];
        float w3 = Ws[(k4 * 4 + 3) * FEAT + lane];
        #pragma unroll
        for (int r = 0; r < 8; ++r) {
            float4 xv = Xs4[(wrow + r) * 16 + k4];   // wave-uniform addr -> LDS broadcast
            acc[r] = fmaf(xv.x, w0, acc[r]);
            acc[r] = fmaf(xv.y, w1, acc[r]);
            acc[r] = fmaf(xv.z, w2, acc[r]);
            acc[r] = fmaf(xv.w, w3, acc[r]);
        }
    }

    float as_w = att_s[lane], ad_w = att_d[lane];
    #pragma unroll
    for (int r = 0; r < 8; ++r) {
        int row = row0 + wrow + r;
        if (row >= N) break;
        H[(size_t)row * FEAT + lane] = acc[r];
        float sv = acc[r] * as_w;
        float dv = acc[r] * ad_w;
        #pragma unroll
        for (int off = 32; off; off >>= 1) {
            sv += __shfl_xor(sv, off, 64);
            dv += __shfl_xor(dv, off, 64);
        }
        if (lane == 0) { a_src[row] = sv; a_dst[row] = dv; }
    }
}

// ---------- fused per-node softmax + aggregate (flash-style) ----------
__global__ void fused_agg_kernel(const int* __restrict__ rowptr, const int2* __restrict__ epack,
                                 const float* __restrict__ a_src, const float* __restrict__ a_dst,
                                 const float* __restrict__ cptr, const float* __restrict__ H,
                                 const float* __restrict__ bias, float* __restrict__ OUT, int N) {
    int wave = threadIdx.x >> 6, lane = threadIdx.x & 63;
    int node = blockIdx.x * (blockDim.x >> 6) + wave;
    if (node >= N) return;
    int beg = rowptr[node], end = rowptr[node + 1];
    float c = *cptr;
    float adn = a_dst[node];
    float bval = bias[lane];
    float m = -INFINITY, den = 0.0f;
    float acc0 = 0.f, acc1 = 0.f, acc2 = 0.f, acc3 = 0.f;

    for (int base = beg; base < end; base += 64) {
        int j = base + lane;
        int s = 0;
        float l = -INFINITY;
        if (j < end) {
            int2 v = epack[j];
            s = v.x;
            float ea = __int_as_float(v.y);
            l = a_src[s] + adn + c * ea;
            l = (l > 0.0f) ? l : NEG_SLOPE * l;
        }
        // chunk max
        float cm = l;
        #pragma unroll
        for (int off = 32; off; off >>= 1) cm = fmaxf(cm, __shfl_xor(cm, off, 64));
        if (cm > m) {
            float sc = __expf(m - cm);   // first chunk: exp(-inf)=0, acc/den are 0 anyway
            acc0 *= sc; acc1 *= sc; acc2 *= sc; acc3 *= sc;
            den *= sc;
            m = cm;
        }
        float w = (j < end) ? __expf(l - m) : 0.0f;
        // chunk denominator via butterfly
        float ws = w;
        #pragma unroll
        for (int off = 32; off; off >>= 1) ws += __shfl_xor(ws, off, 64);
        den += ws;

        int cnt = end - base; if (cnt > 64) cnt = 64;
        int k = 0;
        for (; k + 3 < cnt; k += 4) {
            int s0 = __shfl(s, k, 64),     s1 = __shfl(s, k + 1, 64);
            int s2 = __shfl(s, k + 2, 64), s3 = __shfl(s, k + 3, 64);
            float w0 = __shfl(w, k, 64),     w1 = __shfl(w, k + 1, 64);
            float w2 = __shfl(w, k + 2, 64), w3 = __shfl(w, k + 3, 64);
            acc0 = fmaf(w0, H[(size_t)s0 * FEAT + lane], acc0);
            acc1 = fmaf(w1, H[(size_t)s1 * FEAT + lane], acc1);
            acc2 = fmaf(w2, H[(size_t)s2 * FEAT + lane], acc2);
            acc3 = fmaf(w3, H[(size_t)s3 * FEAT + lane], acc3);
        }
        for (; k < cnt; ++k) {
            int sk = __shfl(s, k, 64);
            float wk = __shfl(w, k, 64);
            acc0 = fmaf(wk, H[(size_t)sk * FEAT + lane], acc0);
        }
    }
    float acc = (acc0 + acc1) + (acc2 + acc3);
    OUT[(size_t)node * FEAT + lane] = acc / (den + 1e-16f) + bval;
}

// ---------- host ----------

static inline size_t align256(size_t x) { return (x + 255) & ~size_t(255); }

extern "C" void kernel_launch(void* const* d_in, const int* in_sizes, int n_in,
                              void* d_out, int out_size, void* d_ws, size_t ws_size,
                              hipStream_t stream) {
    const float* x        = (const float*)d_in[0];
    const int*   eidx     = (const int*)d_in[1];
    const float* eattr    = (const float*)d_in[2];
    const float* W1       = (const float*)d_in[3];
    const float* att_s1   = (const float*)d_in[4];
    const float* att_d1   = (const float*)d_in[5];
    const float* We1      = (const float*)d_in[6];
    const float* att_e1   = (const float*)d_in[7];
    const float* b1       = (const float*)d_in[8];
    const float* W2       = (const float*)d_in[9];
    const float* att_s2   = (const float*)d_in[10];
    const float* att_d2   = (const float*)d_in[11];
    const float* We2      = (const float*)d_in[12];
    const float* att_e2   = (const float*)d_in[13];
    const float* b2       = (const float*)d_in[14];
    float* OUT = (float*)d_out;

    const int N = in_sizes[0] / FEAT;
    const int E = in_sizes[2];
    const int* src = eidx;
    const int* dst = eidx + E;

    // workspace layout
    char* ws = (char*)d_ws;
    size_t off = 0;
    float* h     = (float*)(ws + off); off = align256(off + (size_t)N * FEAT * 4);
    float* out1  = (float*)(ws + off); off = align256(off + (size_t)N * FEAT * 4);
    float* a_src = (float*)(ws + off); off = align256(off + (size_t)N * 4);
    float* a_dst = (float*)(ws + off); off = align256(off + (size_t)N * 4);
    int*   deg    = (int*)(ws + off); off = align256(off + (size_t)N * 4);
    int*   partial= (int*)(ws + off); off = align256(off + (size_t)N * 4);
    int*   rowptr = (int*)(ws + off); off = align256(off + (size_t)(N + 1) * 4);
    int*   cursor = (int*)(ws + off); off = align256(off + (size_t)N * 4);
    int*   bsum   = (int*)(ws + off); off = align256(off + 1024 * 4);
    int*   bsumS  = (int*)(ws + off); off = align256(off + 1024 * 4);
    int2*  epack  = (int2*)(ws + off); off = align256(off + (size_t)E * 8);
    float* cbuf  = (float*)(ws + off); off = align256(off + 2 * 4);
    (void)ws_size;

    const int nb         = (N + 255) / 256;
    const int gemmBlocks = (N + TROWS - 1) / TROWS;
    const int edgeBlocks = (E + 255) / 256;
    const int aggBlocks  = (N + 3) / 4;

    prep_kernel<<<2, 64, 0, stream>>>(We1, att_e1, We2, att_e2, cbuf);

    // ===== CSR build (once; shared by both layers) =====
    hipMemsetAsync(deg, 0, (size_t)N * 4, stream);
    hist_kernel<<<edgeBlocks, 256, 0, stream>>>(dst, deg, E);
    scan_block_kernel<<<nb, 256, 0, stream>>>(deg, partial, bsum, N);
    scan_block_kernel<<<1, 256, 0, stream>>>(bsum, bsumS, nullptr, nb);
    scan_finalize_kernel<<<nb, 256, 0, stream>>>(partial, bsumS, deg, rowptr, cursor, N, E);
    scatter_kernel<<<edgeBlocks, 256, 0, stream>>>(src, dst, eattr, cursor, epack, E);

    // ===== layer 1 =====
    gemm_att_kernel<false><<<gemmBlocks, 256, 0, stream>>>(x, W1, att_s1, att_d1, h, a_src, a_dst, N);
    fused_agg_kernel<<<aggBlocks, 256, 0, stream>>>(rowptr, epack, a_src, a_dst, cbuf + 0, h, b1, out1, N);

    // ===== layer 2 (ReLU applied on input read inside gemm) =====
    gemm_att_kernel<true><<<gemmBlocks, 256, 0, stream>>>(out1, W2, att_s2, att_d2, h, a_src, a_dst, N);
    fused_agg_kernel<<<aggBlocks, 256, 0, stream>>>(rowptr, epack, a_src, a_dst, cbuf + 1, h, b2, OUT, N);
}

// Round 4
// 236.622 us; speedup vs baseline: 2.8141x; 1.3379x over previous
//
#include <hip/hip_runtime.h>
#include <cstdint>

#define FEAT 64
#define NEG_SLOPE 0.2f

// ---------- prep: cbuf[b] = dot(We_b, att_e_b) ----------
__global__ void prep_kernel(const float* __restrict__ We1, const float* __restrict__ ae1,
                            const float* __restrict__ We2, const float* __restrict__ ae2,
                            float* __restrict__ cbuf) {
    int lane = threadIdx.x;
    const float* a = blockIdx.x ? We2 : We1;
    const float* b = blockIdx.x ? ae2 : ae1;
    float v = a[lane] * b[lane];
    #pragma unroll
    for (int off = 32; off; off >>= 1) v += __shfl_xor(v, off, 64);
    if (lane == 0) cbuf[blockIdx.x] = v;
}

// ---------- CSR build ----------

__global__ void hist_kernel(const int* __restrict__ dst, int* __restrict__ deg, int E) {
    int e = blockIdx.x * blockDim.x + threadIdx.x;
    if (e < E) atomicAdd(&deg[dst[e]], 1);
}

__global__ void scan_block_kernel(const int* __restrict__ in, int* __restrict__ partial,
                                  int* __restrict__ bsum, int n) {
    int tid = threadIdx.x;
    int i = blockIdx.x * 256 + tid;
    int lane = tid & 63, wave = tid >> 6;
    int v = (i < n) ? in[i] : 0;
    #pragma unroll
    for (int off = 1; off < 64; off <<= 1) {
        int t = __shfl_up(v, off, 64);
        if (lane >= off) v += t;
    }
    __shared__ int wsum[4];
    if (lane == 63) wsum[wave] = v;
    __syncthreads();
    int add = 0;
    for (int w = 0; w < wave; ++w) add += wsum[w];
    v += add;
    if (i < n) partial[i] = v;
    if (tid == 255 && bsum) bsum[blockIdx.x] = v;
}

__global__ void scan_finalize_kernel(const int* __restrict__ partial, const int* __restrict__ bsumS,
                                     const int* __restrict__ deg, int* __restrict__ rowptr,
                                     int* __restrict__ cursor, int N, int E) {
    int i = blockIdx.x * 256 + threadIdx.x;
    if (i >= N) return;
    int T = partial[i] + (blockIdx.x > 0 ? bsumS[blockIdx.x - 1] : 0);
    int r = T - deg[i];            // exclusive scan
    rowptr[i] = r;
    cursor[i] = r;
    if (i == N - 1) rowptr[N] = E;
}

__global__ void scatter_kernel(const int* __restrict__ src, const int* __restrict__ dst,
                               const float* __restrict__ eattr, int* __restrict__ cursor,
                               int2* __restrict__ epack, int E) {
    int e = blockIdx.x * blockDim.x + threadIdx.x;
    if (e >= E) return;
    int pos = atomicAdd(&cursor[dst[e]], 1);
    epack[pos] = make_int2(src[e], __float_as_int(eattr[e]));
}

// ---------- GEMM (h = act(x) @ W) fused with attention dots ----------
template <bool RELU_IN>
__global__ __launch_bounds__(256) void gemm_att_kernel(
        const float* __restrict__ X, const float* __restrict__ W,
        const float* __restrict__ att_s, const float* __restrict__ att_d,
        float* __restrict__ H, float* __restrict__ a_src,
        float* __restrict__ a_dst, int N) {
    __shared__ float Ws[FEAT * FEAT];
    int tid = threadIdx.x, wave = tid >> 6, lane = tid & 63;

    const float4* W4 = (const float4*)W;
    float4* Ws4 = (float4*)Ws;
    #pragma unroll
    for (int i = 0; i < 4; ++i) Ws4[tid + i * 256] = W4[tid + i * 256];

    int row0 = blockIdx.x * 32 + wave * 8;
    float xv[8];
    #pragma unroll
    for (int r = 0; r < 8; ++r) {
        int row = row0 + r;
        float v = 0.f;
        if (row < N) v = X[(size_t)row * FEAT + lane];
        if (RELU_IN) v = fmaxf(v, 0.f);
        xv[r] = v;
    }
    __syncthreads();

    float acc[8] = {0.f, 0.f, 0.f, 0.f, 0.f, 0.f, 0.f, 0.f};
    #pragma unroll
    for (int k = 0; k < FEAT; ++k) {
        float wk = Ws[k * FEAT + lane];
        #pragma unroll
        for (int r = 0; r < 8; ++r) {
            float xk = __uint_as_float(__builtin_amdgcn_readlane(__float_as_uint(xv[r]), k));
            acc[r] = fmaf(xk, wk, acc[r]);
        }
    }

    float as_w = att_s[lane], ad_w = att_d[lane];
    #pragma unroll
    for (int r = 0; r < 8; ++r) {
        int row = row0 + r;
        if (row >= N) break;
        H[(size_t)row * FEAT + lane] = acc[r];
        float sv = acc[r] * as_w;
        float dv = acc[r] * ad_w;
        #pragma unroll
        for (int off = 32; off; off >>= 1) {
            sv += __shfl_xor(sv, off, 64);
            dv += __shfl_xor(dv, off, 64);
        }
        if (lane == 0) { a_src[row] = sv; a_dst[row] = dv; }
    }
}

// ---------- fused per-node softmax + aggregate ----------
__global__ __launch_bounds__(256) void fused_agg_kernel(
        const int* __restrict__ rowptr, const int2* __restrict__ epack,
        const float* __restrict__ a_src, const float* __restrict__ a_dst,
        const float* __restrict__ cptr, const float* __restrict__ H,
        const float* __restrict__ bias, float* __restrict__ OUT, int N) {
    int tid = threadIdx.x;
    int wave = tid >> 6, lane = tid & 63;
    int grp = lane >> 4, gl = lane & 15;
    int grpBase = grp << 4;
    int node = blockIdx.x * 16 + wave * 4 + grp;
    bool valid = node < N;
    int beg = 0, end = 0;
    if (valid) { beg = rowptr[node]; end = rowptr[node + 1]; }
    float c = *cptr;
    float adn = valid ? a_dst[node] : 0.f;

    float m = -INFINITY, den = 0.f;
    float4 a0 = {0,0,0,0}, a1 = {0,0,0,0}, a2 = {0,0,0,0}, a3 = {0,0,0,0};

    int nchunk = (end - beg + 15) >> 4;
    int wc = nchunk;
    wc = max(wc, __shfl_xor(wc, 16, 64));
    wc = max(wc, __shfl_xor(wc, 32, 64));

    const float4* H4 = (const float4*)H;
    for (int ch = 0; ch < wc; ++ch) {
        int j = beg + ch * 16 + gl;
        int s = 0;
        float l = -INFINITY;
        if (j < end) {
            int2 v = epack[j];
            s = v.x;
            l = fmaf(c, __int_as_float(v.y), a_src[s] + adn);
            l = (l > 0.f) ? l : NEG_SLOPE * l;
        }
        float cm = l;
        cm = fmaxf(cm, __shfl_xor(cm, 1, 64));
        cm = fmaxf(cm, __shfl_xor(cm, 2, 64));
        cm = fmaxf(cm, __shfl_xor(cm, 4, 64));
        cm = fmaxf(cm, __shfl_xor(cm, 8, 64));
        if (cm > m) {
            float sc = __expf(m - cm);
            a0.x*=sc; a0.y*=sc; a0.z*=sc; a0.w*=sc;
            a1.x*=sc; a1.y*=sc; a1.z*=sc; a1.w*=sc;
            a2.x*=sc; a2.y*=sc; a2.z*=sc; a2.w*=sc;
            a3.x*=sc; a3.y*=sc; a3.z*=sc; a3.w*=sc;
            den *= sc;
            m = cm;
        }
        float w = (j < end) ? __expf(l - m) : 0.f;
        float ws = w;
        ws += __shfl_xor(ws, 1, 64);
        ws += __shfl_xor(ws, 2, 64);
        ws += __shfl_xor(ws, 4, 64);
        ws += __shfl_xor(ws, 8, 64);
        den += ws;

        int cnt = end - (beg + ch * 16);
        cnt = min(max(cnt, 0), 16);
        int mc = cnt;
        mc = max(mc, __shfl_xor(mc, 16, 64));
        mc = max(mc, __shfl_xor(mc, 32, 64));

        int k = 0;
        for (; k + 3 < mc; k += 4) {
            int   s0 = __shfl(s, grpBase + k,     64);
            int   s1 = __shfl(s, grpBase + k + 1, 64);
            int   s2 = __shfl(s, grpBase + k + 2, 64);
            int   s3 = __shfl(s, grpBase + k + 3, 64);
            float w0 = __shfl(w, grpBase + k,     64);
            float w1 = __shfl(w, grpBase + k + 1, 64);
            float w2 = __shfl(w, grpBase + k + 2, 64);
            float w3 = __shfl(w, grpBase + k + 3, 64);
            float4 h0 = H4[(size_t)s0 * 16 + gl];
            float4 h1 = H4[(size_t)s1 * 16 + gl];
            float4 h2 = H4[(size_t)s2 * 16 + gl];
            float4 h3 = H4[(size_t)s3 * 16 + gl];
            a0.x = fmaf(w0, h0.x, a0.x); a0.y = fmaf(w0, h0.y, a0.y);
            a0.z = fmaf(w0, h0.z, a0.z); a0.w = fmaf(w0, h0.w, a0.w);
            a1.x = fmaf(w1, h1.x, a1.x); a1.y = fmaf(w1, h1.y, a1.y);
            a1.z = fmaf(w1, h1.z, a1.z); a1.w = fmaf(w1, h1.w, a1.w);
            a2.x = fmaf(w2, h2.x, a2.x); a2.y = fmaf(w2, h2.y, a2.y);
            a2.z = fmaf(w2, h2.z, a2.z); a2.w = fmaf(w2, h2.w, a2.w);
            a3.x = fmaf(w3, h3.x, a3.x); a3.y = fmaf(w3, h3.y, a3.y);
            a3.z = fmaf(w3, h3.z, a3.z); a3.w = fmaf(w3, h3.w, a3.w);
        }
        for (; k < mc; ++k) {
            int   sk = __shfl(s, grpBase + k, 64);
            float wk = __shfl(w, grpBase + k, 64);
            float4 hv = H4[(size_t)sk * 16 + gl];
            a0.x = fmaf(wk, hv.x, a0.x); a0.y = fmaf(wk, hv.y, a0.y);
            a0.z = fmaf(wk, hv.z, a0.z); a0.w = fmaf(wk, hv.w, a0.w);
        }
    }

    if (valid) {
        float4 b4 = ((const float4*)bias)[gl];
        float inv = 1.f / (den + 1e-16f);
        float4 o;
        o.x = (a0.x + a1.x + a2.x + a3.x) * inv + b4.x;
        o.y = (a0.y + a1.y + a2.y + a3.y) * inv + b4.y;
        o.z = (a0.z + a1.z + a2.z + a3.z) * inv + b4.z;
        o.w = (a0.w + a1.w + a2.w + a3.w) * inv + b4.w;
        ((float4*)OUT)[(size_t)node * 16 + gl] = o;
    }
}

// ---------- host ----------

static inline size_t align256(size_t x) { return (x + 255) & ~size_t(255); }

extern "C" void kernel_launch(void* const* d_in, const int* in_sizes, int n_in,
                              void* d_out, int out_size, void* d_ws, size_t ws_size,
                              hipStream_t stream) {
    const float* x        = (const float*)d_in[0];
    const int*   eidx     = (const int*)d_in[1];
    const float* eattr    = (const float*)d_in[2];
    const float* W1       = (const float*)d_in[3];
    const float* att_s1   = (const float*)d_in[4];
    const float* att_d1   = (const float*)d_in[5];
    const float* We1      = (const float*)d_in[6];
    const float* att_e1   = (const float*)d_in[7];
    const float* b1       = (const float*)d_in[8];
    const float* W2       = (const float*)d_in[9];
    const float* att_s2   = (const float*)d_in[10];
    const float* att_d2   = (const float*)d_in[11];
    const float* We2      = (const float*)d_in[12];
    const float* att_e2   = (const float*)d_in[13];
    const float* b2       = (const float*)d_in[14];
    float* OUT = (float*)d_out;

    const int N = in_sizes[0] / FEAT;
    const int E = in_sizes[2];
    const int* src = eidx;
    const int* dst = eidx + E;

    char* ws = (char*)d_ws;
    size_t off = 0;
    float* h     = (float*)(ws + off); off = align256(off + (size_t)N * FEAT * 4);
    float* out1  = (float*)(ws + off); off = align256(off + (size_t)N * FEAT * 4);
    float* a_src = (float*)(ws + off); off = align256(off + (size_t)N * 4);
    float* a_dst = (float*)(ws + off); off = align256(off + (size_t)N * 4);
    int*   deg    = (int*)(ws + off); off = align256(off + (size_t)N * 4);
    int*   partial= (int*)(ws + off); off = align256(off + (size_t)N * 4);
    int*   rowptr = (int*)(ws + off); off = align256(off + (size_t)(N + 1) * 4);
    int*   cursor = (int*)(ws + off); off = align256(off + (size_t)N * 4);
    int*   bsum   = (int*)(ws + off); off = align256(off + 1024 * 4);
    int*   bsumS  = (int*)(ws + off); off = align256(off + 1024 * 4);
    int2*  epack  = (int2*)(ws + off); off = align256(off + (size_t)E * 8);
    float* cbuf  = (float*)(ws + off); off = align256(off + 2 * 4);
    (void)ws_size;

    const int nb         = (N + 255) / 256;
    const int gemmBlocks = (N + 31) / 32;
    const int edgeBlocks = (E + 255) / 256;
    const int aggBlocks  = (N + 15) / 16;

    prep_kernel<<<2, 64, 0, stream>>>(We1, att_e1, We2, att_e2, cbuf);

    hipMemsetAsync(deg, 0, (size_t)N * 4, stream);
    hist_kernel<<<edgeBlocks, 256, 0, stream>>>(dst, deg, E);
    scan_block_kernel<<<nb, 256, 0, stream>>>(deg, partial, bsum, N);
    scan_block_kernel<<<1, 256, 0, stream>>>(bsum, bsumS, nullptr, nb);
    scan_finalize_kernel<<<nb, 256, 0, stream>>>(partial, bsumS, deg, rowptr, cursor, N, E);
    scatter_kernel<<<edgeBlocks, 256, 0, stream>>>(src, dst, eattr, cursor, epack, E);

    gemm_att_kernel<false><<<gemmBlocks, 256, 0, stream>>>(x, W1, att_s1, att_d1, h, a_src, a_dst, N);
    fused_agg_kernel<<<aggBlocks, 256, 0, stream>>>(rowptr, epack, a_src, a_dst, cbuf + 0, h, b1, out1, N);

    gemm_att_kernel<true><<<gemmBlocks, 256, 0, stream>>>(out1, W2, att_s2, att_d2, h, a_src, a_dst, N);
    fused_agg_kernel<<<aggBlocks, 256, 0, stream>>>(rowptr, epack, a_src, a_dst, cbuf + 1, h, b2, OUT, N);
}